// Round 5
// baseline (83.448 us; speedup 1.0000x reference)
//
#include <hip/hip_runtime.h>

// images: (B=8, H=128, W=128, C=32) f32; k=5, pad=2; out: (B,H,W,800) f32
// out[b,h,w,(kh*5+kw)*32+c] = images[b, h+kh-2, w+kw-2, c]  (0 if OOB)
//
// Stage-once streaming: 256 persistent blocks (1/CU) x 1024 threads.
// Each block owns 4 output rows (b, h0..h0+3); stages ALL 8 input rows it
// needs (h0-2..h0+5, 128 KB LDS, slot = row & 7 — collision-free) with one
// barrier, then streams 100 uninterrupted coalesced float4 store iters.
// No barriers in the store stream -> no vmcnt(0) store-drain bubbles.
// Plain stores (not NT): the fill kernel proves plain stores hit 6.9 TB/s;
// input is staged once up front so L2 write pollution is irrelevant.

constexpr int PAD  = 2;
constexpr int CH4  = 8;                         // 32 ch = 8 float4
constexpr int HH   = 128, WW = 128, BB = 8;
constexpr int ROW_F4     = WW * CH4;            // 1024 float4 = 16 KB per input row
constexpr int OUT_ROW_F4 = WW * 25 * CH4;       // 25600 float4 per output row
constexpr int THREADS    = 1024;
constexpr int ROWS_PER_BLK = 4;
constexpr int NWG        = BB * HH / ROWS_PER_BLK;  // 256 blocks = 1/CU
constexpr int SLOTS      = 8;                   // staged rows (h0-2 .. h0+5)

typedef float f32x4 __attribute__((ext_vector_type(4)));

__global__ void __launch_bounds__(THREADS) extract_patch_kernel(
        const f32x4* __restrict__ in, f32x4* __restrict__ out) {
    __shared__ f32x4 lds[SLOTS * ROW_F4];       // 128 KB

    // XCD-chunked bijective swizzle (nwg=256, 256%8==0): each XCD owns one
    // image b (2.1 MB < 4 MiB L2) -> staging reads are L2-local.
    int bid = blockIdx.x;
    int lin = (bid & 7) * (NWG / 8) + (bid >> 3);
    int b  = lin >> 5;
    int h0 = (lin & 31) * ROWS_PER_BLK;

    int tid = threadIdx.x;
    const f32x4* img = in + (size_t)b * HH * ROW_F4;

    // ---- Stage all 8 needed rows once (zeros for OOB), one barrier ----
    {
        f32x4 v0[SLOTS];
        #pragma unroll
        for (int i = 0; i < SLOTS; ++i) {       // 8 independent loads in flight
            int gr = h0 - PAD + i;              // h0-2 .. h0+5
            v0[i] = 0.f;
            if ((unsigned)gr < (unsigned)HH)    // block-uniform branch
                v0[i] = img[(size_t)gr * ROW_F4 + tid];
        }
        #pragma unroll
        for (int i = 0; i < SLOTS; ++i) {
            int gr = h0 - PAD + i;
            // slots gr&7 are pairwise distinct over 8 consecutive rows
            lds[(gr & (SLOTS - 1)) * ROW_F4 + tid] = v0[i];
        }
    }
    __syncthreads();                            // the ONLY barrier

    // ---- Stream 4 output rows: 100 coalesced float4 stores/thread ----
    for (int r = 0; r < ROWS_PER_BLK; ++r) {
        int h = h0 + r;
        f32x4* rowout = out + ((size_t)lin * ROWS_PER_BLK + r) * OUT_ROW_F4;
        #pragma unroll 5
        for (int it = 0; it < OUT_ROW_F4 / THREADS; ++it) {   // 25 iters
            int j  = tid + it * THREADS;
            int w  = j / 200;                    // 200 float4 per w
            int rr = j - w * 200;
            int kq = rr >> 3;                    // kh*5+kw (0..24)
            int c4 = rr & 7;
            int kh = (kq * 205) >> 10;           // kq/5 exact for 0..24
            int kw = kq - kh * 5;
            int pc = w + kw - PAD;               // padded col, -2..129
            int gr = h + kh - PAD;               // staged row
            int slot = gr & (SLOTS - 1);
            bool ok = (unsigned)pc < (unsigned)WW;
            f32x4 v = lds[slot * ROW_F4 + (pc & (WW - 1)) * CH4 + c4];
            f32x4 z = 0.f;
            v = ok ? v : z;                      // branchless col padding
            rowout[j] = v;                       // plain coalesced store
        }
    }
}

extern "C" void kernel_launch(void* const* d_in, const int* in_sizes, int n_in,
                              void* d_out, int out_size, void* d_ws, size_t ws_size,
                              hipStream_t stream) {
    const f32x4* images = (const f32x4*)d_in[0];
    f32x4* out = (f32x4*)d_out;
    extract_patch_kernel<<<NWG, THREADS, 0, stream>>>(images, out);
}

// Round 6
// 78.880 us; speedup vs baseline: 1.0579x; 1.0579x over previous
//
#include <hip/hip_runtime.h>

// images: (B=8, H=128, W=128, C=32) f32; k=5, pad=2; out: (B,H,W,800) f32
// out[b,h,w,(kh*5+kw)*32+c] = images[b, h+kh-2, w+kw-2, c]  (0 if OOB)
//
// v6 = v5 structure + NT stores (single-variable change).
// Stage-once streaming: 256 persistent blocks (1/CU) x 1024 threads.
// Each block owns 4 output rows (b, h0..h0+3); stages ALL 8 input rows it
// needs (h0-2..h0+5, 128 KB LDS, slot = row & 7 — collision-free) behind
// one barrier, then streams 100 uninterrupted coalesced float4 NT stores.
// NT matters: v4(NT)=79.8 vs v5(plain)=83.4 with otherwise-equal read amp —
// the 419 MB write stream must bypass L2 (write-allocate/writeback cost).

constexpr int PAD  = 2;
constexpr int CH4  = 8;                         // 32 ch = 8 float4
constexpr int HH   = 128, WW = 128, BB = 8;
constexpr int ROW_F4     = WW * CH4;            // 1024 float4 = 16 KB per input row
constexpr int OUT_ROW_F4 = WW * 25 * CH4;       // 25600 float4 per output row
constexpr int THREADS    = 1024;
constexpr int ROWS_PER_BLK = 4;
constexpr int NWG        = BB * HH / ROWS_PER_BLK;  // 256 blocks = 1/CU
constexpr int SLOTS      = 8;                   // staged rows (h0-2 .. h0+5)

typedef float f32x4 __attribute__((ext_vector_type(4)));

__global__ void __launch_bounds__(THREADS) extract_patch_kernel(
        const f32x4* __restrict__ in, f32x4* __restrict__ out) {
    __shared__ f32x4 lds[SLOTS * ROW_F4];       // 128 KB

    // XCD-chunked bijective swizzle (nwg=256, 256%8==0): each XCD owns one
    // image b (2.1 MB < 4 MiB L2) -> staging reads are L2-local.
    int bid = blockIdx.x;
    int lin = (bid & 7) * (NWG / 8) + (bid >> 3);
    int b  = lin >> 5;
    int h0 = (lin & 31) * ROWS_PER_BLK;

    int tid = threadIdx.x;
    const f32x4* img = in + (size_t)b * HH * ROW_F4;

    // ---- Stage all 8 needed rows once (zeros for OOB), one barrier ----
    {
        f32x4 v0[SLOTS];
        #pragma unroll
        for (int i = 0; i < SLOTS; ++i) {       // 8 independent loads in flight
            int gr = h0 - PAD + i;              // h0-2 .. h0+5
            v0[i] = 0.f;
            if ((unsigned)gr < (unsigned)HH)    // block-uniform branch
                v0[i] = img[(size_t)gr * ROW_F4 + tid];
        }
        #pragma unroll
        for (int i = 0; i < SLOTS; ++i) {
            int gr = h0 - PAD + i;
            // slots gr&7 are pairwise distinct over 8 consecutive rows
            lds[(gr & (SLOTS - 1)) * ROW_F4 + tid] = v0[i];
        }
    }
    __syncthreads();                            // the ONLY barrier

    // ---- Stream 4 output rows: 100 coalesced float4 NT stores/thread ----
    for (int r = 0; r < ROWS_PER_BLK; ++r) {
        int h = h0 + r;
        f32x4* rowout = out + ((size_t)lin * ROWS_PER_BLK + r) * OUT_ROW_F4;
        #pragma unroll 5
        for (int it = 0; it < OUT_ROW_F4 / THREADS; ++it) {   // 25 iters
            int j  = tid + it * THREADS;
            int w  = j / 200;                    // 200 float4 per w
            int rr = j - w * 200;
            int kq = rr >> 3;                    // kh*5+kw (0..24)
            int c4 = rr & 7;
            int kh = (kq * 205) >> 10;           // kq/5 exact for 0..24
            int kw = kq - kh * 5;
            int pc = w + kw - PAD;               // padded col, -2..129
            int gr = h + kh - PAD;               // staged row
            int slot = gr & (SLOTS - 1);
            bool ok = (unsigned)pc < (unsigned)WW;
            f32x4 v = lds[slot * ROW_F4 + (pc & (WW - 1)) * CH4 + c4];
            f32x4 z = 0.f;
            v = ok ? v : z;                      // branchless col padding
            __builtin_nontemporal_store(v, &rowout[j]);
        }
    }
}

extern "C" void kernel_launch(void* const* d_in, const int* in_sizes, int n_in,
                              void* d_out, int out_size, void* d_ws, size_t ws_size,
                              hipStream_t stream) {
    const f32x4* images = (const f32x4*)d_in[0];
    f32x4* out = (f32x4*)d_out;
    extract_patch_kernel<<<NWG, THREADS, 0, stream>>>(images, out);
}

// Round 8
// 75.762 us; speedup vs baseline: 1.1014x; 1.0412x over previous
//
#include <hip/hip_runtime.h>

// images: (B=8, H=128, W=128, C=32) f32; k=5, pad=2; out: (B,H,W,800) f32
// out[b,h,w,(kh*5+kw)*32+c] = images[b, h+kh-2, w+kw-2, c]  (0 if OOB)
//
// v8 = v7 with corrected geometry (v7 launched 256 blocks with a 1024-block
// index mapping -> wrong sources). 1024 blocks x 1024 threads, ONE output
// row per block: b = lin>>7, h = lin&127, 25 store iters.
// No LDS, no barriers, no stage prologue. XCD-chunked swizzle gives each
// XCD exactly one image b (2.1 MB < 4 MiB per-XCD L2) -> 25x-reused input
// reads are L2 hits. NT stores (proven +4.5us vs plain, v5 vs v6) keep the
// 419 MB write stream out of L2 so the input stays resident.

constexpr int PAD  = 2;
constexpr int CH4  = 8;                         // 32 ch = 8 float4
constexpr int HH   = 128, WW = 128, BB = 8;
constexpr int ROW_F4     = WW * CH4;            // 1024 float4 per input row
constexpr int OUT_ROW_F4 = WW * 25 * CH4;       // 25600 float4 per output row
constexpr int THREADS    = 1024;
constexpr int NWG        = BB * HH;             // 1024 blocks, 1 output row each

typedef float f32x4 __attribute__((ext_vector_type(4)));

__global__ void __launch_bounds__(THREADS) extract_patch_kernel(
        const f32x4* __restrict__ in, f32x4* __restrict__ out) {
    // XCD-chunked bijective swizzle (nwg=1024, 1024%8==0): XCD x owns
    // lin in [x*128, (x+1)*128) == image b = x.
    int bid = blockIdx.x;
    int lin = (bid & 7) * (NWG / 8) + (bid >> 3);
    int b = lin >> 7;                           // 0..7, one image per XCD
    int h = lin & (HH - 1);                     // 0..127

    int tid = threadIdx.x;
    const f32x4* img = in + (size_t)b * HH * ROW_F4;
    f32x4* rowout = out + (size_t)lin * OUT_ROW_F4;

    #pragma unroll 5
    for (int it = 0; it < OUT_ROW_F4 / THREADS; ++it) {   // 25 iters
        int j  = tid + it * THREADS;
        int w  = j / 200;                        // 200 float4 per w
        int rr = j - w * 200;
        int kq = rr >> 3;                        // kh*5+kw (0..24)
        int c4 = rr & 7;
        int kh = (kq * 205) >> 10;               // kq/5 exact for 0..24
        int kw = kq - kh * 5;
        int pc = w + kw - PAD;                   // padded col, -2..129
        int gr = h + kh - PAD;                   // padded row, -2..129
        bool ok = ((unsigned)pc < (unsigned)WW) &
                  ((unsigned)gr < (unsigned)HH);
        // Clamped address is always legal; OOB value masked to zero.
        f32x4 v = img[(size_t)(gr & (HH - 1)) * ROW_F4
                      + (pc & (WW - 1)) * CH4 + c4];
        f32x4 z = 0.f;
        v = ok ? v : z;                          // branchless padding
        __builtin_nontemporal_store(v, &rowout[j]);
    }
}

extern "C" void kernel_launch(void* const* d_in, const int* in_sizes, int n_in,
                              void* d_out, int out_size, void* d_ws, size_t ws_size,
                              hipStream_t stream) {
    const f32x4* images = (const f32x4*)d_in[0];
    f32x4* out = (f32x4*)d_out;
    extract_patch_kernel<<<NWG, THREADS, 0, stream>>>(images, out);
}